// Round 1
// baseline (223.149 us; speedup 1.0000x reference)
//
#include <hip/hip_runtime.h>
#include <hip/hip_bf16.h>
#include <stdint.h>

// Problem constants (fixed by setup_inputs)
#define TM 16384   // B rows of input
#define TN 4096    // O centers
#define TK 1024    // I feature dim

#define BM 128
#define BN 128
#define BK 32

typedef __attribute__((ext_vector_type(8))) short bf16x8;
typedef __attribute__((ext_vector_type(4))) float f32x4;

static __device__ __forceinline__ ushort f2bf(float x) {
    __hip_bfloat16 h = __float2bfloat16(x);
    return *reinterpret_cast<ushort*>(&h);
}

// Convert one fp32 row (TK elems) to bf16 and emit its sum of squares.
__global__ __launch_bounds__(256) void rowsq_cvt(const float* __restrict__ src,
                                                 ushort* __restrict__ dst,
                                                 float* __restrict__ sq) {
    const int row = blockIdx.x;
    const int t = threadIdx.x;
    const size_t base = (size_t)row * TK + (size_t)t * 4;
    const float4 v = *(const float4*)(src + base);
    float s = v.x * v.x + v.y * v.y + v.z * v.z + v.w * v.w;

    ushort4 b;
    b.x = f2bf(v.x); b.y = f2bf(v.y); b.z = f2bf(v.z); b.w = f2bf(v.w);
    *(ushort4*)(dst + base) = b;

#pragma unroll
    for (int off = 32; off > 0; off >>= 1) s += __shfl_down(s, off);

    __shared__ float red[4];
    const int lane = t & 63, wave = t >> 6;
    if (lane == 0) red[wave] = s;
    __syncthreads();
    if (t == 0) sq[row] = red[0] + red[1] + red[2] + red[3];
}

// f[o] = -1/(2*sigma^2), sigma = exp(log_sigma)
__global__ __launch_bounds__(256) void scale_k(const float* __restrict__ ls,
                                               float* __restrict__ f) {
    const int i = blockIdx.x * 256 + threadIdx.x;
    if (i < TN) f[i] = -0.5f * expf(-2.0f * ls[i]);
}

// 128x128 tile bf16 MFMA GEMM (B^T layout: centers are [TN][TK] row-major)
// with fused RBF epilogue.
__global__ __launch_bounds__(256) void rbf_gemm(const ushort* __restrict__ A,
                                                const ushort* __restrict__ B,
                                                const float* __restrict__ xsq,
                                                const float* __restrict__ csq,
                                                const float* __restrict__ fsc,
                                                float* __restrict__ out) {
    __shared__ __align__(16) ushort As[BM * BK];
    __shared__ __align__(16) ushort Bs[BN * BK];

    const int bn = blockIdx.x;   // N tile
    const int bm = blockIdx.y;   // M tile
    const int tid = threadIdx.x;
    const int lane = tid & 63, wave = tid >> 6;
    const int wr = wave >> 1, wc = wave & 1;      // 2x2 waves, each 64x64 out
    const int lrow = lane & 15, lhi = lane >> 4;  // MFMA fragment coords

    f32x4 acc[4][4];
#pragma unroll
    for (int m = 0; m < 4; ++m)
#pragma unroll
        for (int n = 0; n < 4; ++n)
            acc[m][n] = (f32x4){0.f, 0.f, 0.f, 0.f};

    // Staging: wave w owns tile rows [w*32, w*32+32), two 16-row issues.
    // Per issue a wave's 64 lanes cover 16 rows x 4 slots of 16B (linear LDS).
    const int srow = wave * 32 + (lane >> 2);   // + 16 for issue 1
    const int scol = (lane & 3) * 8;            // bf16 elems (16B slots)
    const ushort* gA = A + (size_t)(bm * BM + srow) * TK + scol;
    const ushort* gB = B + (size_t)(bn * BN + srow) * TK + scol;
    ushort* lA = As + (size_t)(wave * 32) * BK;  // HW adds lane*16B
    ushort* lB = Bs + (size_t)(wave * 32) * BK;

    for (int kt = 0; kt < TK; kt += BK) {
        __syncthreads();  // previous iter's LDS reads done
        __builtin_amdgcn_global_load_lds(
            (const __attribute__((address_space(1))) void*)(gA + kt),
            (__attribute__((address_space(3))) void*)lA, 16, 0, 0);
        __builtin_amdgcn_global_load_lds(
            (const __attribute__((address_space(1))) void*)(gA + kt + 16 * TK),
            (__attribute__((address_space(3))) void*)(lA + 16 * BK), 16, 0, 0);
        __builtin_amdgcn_global_load_lds(
            (const __attribute__((address_space(1))) void*)(gB + kt),
            (__attribute__((address_space(3))) void*)lB, 16, 0, 0);
        __builtin_amdgcn_global_load_lds(
            (const __attribute__((address_space(1))) void*)(gB + kt + 16 * TK),
            (__attribute__((address_space(3))) void*)(lB + 16 * BK), 16, 0, 0);
        __syncthreads();  // staging landed (compiler drains vmcnt before barrier)

        bf16x8 af[4], bfr[4];
#pragma unroll
        for (int m = 0; m < 4; ++m)
            af[m] = *(const bf16x8*)(As + (wr * 64 + m * 16 + lrow) * BK + lhi * 8);
#pragma unroll
        for (int n = 0; n < 4; ++n)
            bfr[n] = *(const bf16x8*)(Bs + (wc * 64 + n * 16 + lrow) * BK + lhi * 8);

#pragma unroll
        for (int m = 0; m < 4; ++m)
#pragma unroll
            for (int n = 0; n < 4; ++n)
                acc[m][n] = __builtin_amdgcn_mfma_f32_16x16x32_bf16(
                    af[m], bfr[n], acc[m][n], 0, 0, 0);
    }

    // Epilogue: d2 = max(x2 + c2 - 2*cross, 0); out = exp(f*d2)
    const int row0 = bm * BM + wr * 64;
    const int col0 = bn * BN + wc * 64;
#pragma unroll
    for (int m = 0; m < 4; ++m) {
        const int rbase = row0 + m * 16 + lhi * 4;
        const float4 xs = *(const float4*)(xsq + rbase);
        const float xv[4] = {xs.x, xs.y, xs.z, xs.w};
#pragma unroll
        for (int n = 0; n < 4; ++n) {
            const int c = col0 + n * 16 + lrow;
            const float cs = csq[c];
            const float f = fsc[c];
#pragma unroll
            for (int j = 0; j < 4; ++j) {
                float d2 = xv[j] + cs - 2.0f * acc[m][n][j];
                d2 = fmaxf(d2, 0.0f);
                out[(size_t)(rbase + j) * TN + c] = __expf(f * d2);
            }
        }
    }
}

extern "C" void kernel_launch(void* const* d_in, const int* in_sizes, int n_in,
                              void* d_out, int out_size, void* d_ws, size_t ws_size,
                              hipStream_t stream) {
    const float* inp = (const float*)d_in[0];  // [TM, TK]
    const float* ctr = (const float*)d_in[1];  // [TN, TK]
    const float* ls  = (const float*)d_in[2];  // [TN]
    float* out = (float*)d_out;

    // workspace layout (~42 MB)
    ushort* Abf = (ushort*)d_ws;
    ushort* Bbf = Abf + (size_t)TM * TK;
    float* xsq = (float*)(Bbf + (size_t)TN * TK);
    float* csq = xsq + TM;
    float* fsc = csq + TN;

    rowsq_cvt<<<TM, 256, 0, stream>>>(inp, Abf, xsq);
    rowsq_cvt<<<TN, 256, 0, stream>>>(ctr, Bbf, csq);
    scale_k<<<(TN + 255) / 256, 256, 0, stream>>>(ls, fsc);

    dim3 grid(TN / BN, TM / BM);
    rbf_gemm<<<grid, 256, 0, stream>>>(Abf, Bbf, xsq, csq, fsc, out);
}

// Round 2
// 185.116 us; speedup vs baseline: 1.2055x; 1.2055x over previous
//
#include <hip/hip_runtime.h>
#include <hip/hip_bf16.h>
#include <stdint.h>

// Problem constants (fixed by setup_inputs)
#define TM 16384   // B rows of input
#define TN 4096    // O centers
#define TK 1024    // I feature dim

// 256x256 8-phase template (learn_hip m201 structure), BK=64, 8 waves.
#define NT (TK / 64)   // 16 K-tiles

typedef __attribute__((ext_vector_type(8))) short bf16x8;
typedef __attribute__((ext_vector_type(4))) float f32x4;

static __device__ __forceinline__ ushort f2bf(float x) {
    __hip_bfloat16 h = __float2bfloat16(x);
    return *reinterpret_cast<ushort*>(&h);
}

// Convert one fp32 row (TK elems) to bf16 and emit its sum of squares.
__global__ __launch_bounds__(256) void rowsq_cvt(const float* __restrict__ src,
                                                 ushort* __restrict__ dst,
                                                 float* __restrict__ sq) {
    const int row = blockIdx.x;
    const int t = threadIdx.x;
    const size_t base = (size_t)row * TK + (size_t)t * 4;
    const float4 v = *(const float4*)(src + base);
    float s = v.x * v.x + v.y * v.y + v.z * v.z + v.w * v.w;

    ushort4 b;
    b.x = f2bf(v.x); b.y = f2bf(v.y); b.z = f2bf(v.z); b.w = f2bf(v.w);
    *(ushort4*)(dst + base) = b;

#pragma unroll
    for (int off = 32; off > 0; off >>= 1) s += __shfl_down(s, off);

    __shared__ float red[4];
    const int lane = t & 63, wave = t >> 6;
    if (lane == 0) red[wave] = s;
    __syncthreads();
    if (t == 0) sq[row] = red[0] + red[1] + red[2] + red[3];
}

// f[o] = -1/(2*sigma^2), sigma = exp(log_sigma)
__global__ __launch_bounds__(256) void scale_k(const float* __restrict__ ls,
                                               float* __restrict__ f) {
    const int i = blockIdx.x * 256 + threadIdx.x;
    if (i < TN) f[i] = -0.5f * expf(-2.0f * ls[i]);
}

// ---- 8-phase 256x256 bf16 MFMA GEMM with fused RBF epilogue ----
// LDS: [buf][A|B] panels of 256x64 bf16 (16384 elems each) = 128 KiB total.
// Swizzle st_16x32: physical byte p holds logical byte p ^ (((p>>9)&1)<<5)
// (involution; applied on the global SOURCE at stage time and on ds_read).

#define STAGE(PAN, G, T, H) do {                                               \
    __builtin_amdgcn_global_load_lds(                                          \
        (const __attribute__((address_space(1))) void*)((G) + (size_t)(H) * 128 * TK + (size_t)(T) * 64), \
        (__attribute__((address_space(3))) void*)((PAN) + (H) * 8192 + wbase), \
        16, 0, 0);                                                             \
    __builtin_amdgcn_global_load_lds(                                          \
        (const __attribute__((address_space(1))) void*)((G) + (size_t)(H) * 128 * TK + 64 * TK + (size_t)(T) * 64), \
        (__attribute__((address_space(3))) void*)((PAN) + (H) * 8192 + 4096 + wbase), \
        16, 0, 0);                                                             \
} while (0)

#define READA(PAN, QM) do {                                                    \
    const ushort* _p = (PAN) + (size_t)(rowA + (QM) * 64) * 64 + cX;           \
    _Pragma("unroll") for (int _i = 0; _i < 4; ++_i)                           \
    _Pragma("unroll") for (int _k = 0; _k < 2; ++_k)                           \
        af[_i][_k] = *(const bf16x8*)(_p + _i * 1024 + _k * 32);               \
} while (0)

#define READB(PAN, QN) do {                                                    \
    const ushort* _p = (PAN) + (size_t)(rowB + (QN) * 32) * 64 + cX;           \
    _Pragma("unroll") for (int _n = 0; _n < 2; ++_n)                           \
    _Pragma("unroll") for (int _k = 0; _k < 2; ++_k)                           \
        bf[(QN) * 2 + _n][_k] = *(const bf16x8*)(_p + _n * 1024 + _k * 32);    \
} while (0)

#define MFMA16(QM, QN)                                                         \
    _Pragma("unroll") for (int _i = 0; _i < 4; ++_i)                           \
    _Pragma("unroll") for (int _n = 0; _n < 2; ++_n)                           \
    _Pragma("unroll") for (int _k = 0; _k < 2; ++_k)                           \
        acc[(QM) * 4 + _i][(QN) * 2 + _n] =                                    \
            __builtin_amdgcn_mfma_f32_16x16x32_bf16(                           \
                af[_i][_k], bf[(QN) * 2 + _n][_k],                             \
                acc[(QM) * 4 + _i][(QN) * 2 + _n], 0, 0, 0)

#define PH_SYNC do {                                                           \
    __builtin_amdgcn_s_barrier();                                              \
    asm volatile("s_waitcnt lgkmcnt(0)" ::: "memory");                         \
    __builtin_amdgcn_sched_barrier(0);                                         \
    __builtin_amdgcn_s_setprio(1);                                             \
} while (0)

#define PH_END do {                                                            \
    __builtin_amdgcn_s_setprio(0);                                             \
    __builtin_amdgcn_s_barrier();                                              \
} while (0)

#define PH_END_VM do {                                                         \
    __builtin_amdgcn_s_setprio(0);                                             \
    asm volatile("s_waitcnt vmcnt(4)" ::: "memory");                           \
    __builtin_amdgcn_s_barrier();                                              \
} while (0)

__global__ __launch_bounds__(512) void rbf_gemm(const ushort* __restrict__ A,
                                                const ushort* __restrict__ B,
                                                const float* __restrict__ xsq,
                                                const float* __restrict__ csq,
                                                const float* __restrict__ fsc,
                                                float* __restrict__ out) {
    __shared__ __align__(16) ushort lds[65536];  // 128 KiB

    // XCD-aware swizzle: grid = 1024 = 8 XCDs x 128 contiguous wgs.
    const int bid = blockIdx.x;
    const int wg = (bid & 7) * 128 + (bid >> 3);
    const int bm = wg >> 4;   // 64 M-tiles
    const int bn = wg & 15;   // 16 N-tiles
    const int row0 = bm * 256;
    const int col0 = bn * 256;

    const int tid = threadIdx.x;
    const int lane = tid & 63, wave = tid >> 6;
    const int wr = wave >> 2, wc = wave & 3;      // 2M x 4N waves, 128x64 out each
    const int lrow = lane & 15, lhi = lane >> 4;  // MFMA fragment coords
    const int cX = (lhi * 8) ^ ((lrow & 4) << 2); // swizzled ds_read col (elems)
    const int rowA = wr * 128 + lrow;
    const int rowB = wc * 64 + lrow;
    const int wbase = wave * 512;                 // elems: wave*1024B staging slice

    // Per-lane staging source: linear LDS slot -> inverse-swizzled global col.
    const int srow = tid >> 3;
    const int scol = ((tid & 7) * 8) ^ ((tid & 32) >> 1);  // elems
    const ushort* gAl = A + (size_t)(row0 + srow) * TK + scol;
    const ushort* gBl = B + (size_t)(col0 + srow) * TK + scol;

    ushort* pA0 = lds;           // buf0 A (even K-tiles)
    ushort* pB0 = lds + 16384;   // buf0 B
    ushort* pA1 = lds + 32768;   // buf1 A (odd K-tiles)
    ushort* pB1 = lds + 49152;   // buf1 B

    f32x4 acc[8][4];
#pragma unroll
    for (int m = 0; m < 8; ++m)
#pragma unroll
        for (int n = 0; n < 4; ++n)
            acc[m][n] = (f32x4){0.f, 0.f, 0.f, 0.f};

    bf16x8 af[4][2];  // current A quadrant (4 m-frags x 2 k-steps)
    bf16x8 bf[4][2];  // all B frags for current tile (4 n-frags x 2 k-steps)

    // Prologue: t0 fully (8 loads) + t1.B halves (4 loads); keep t1.B in flight.
    STAGE(pB0, gBl, 0, 0); STAGE(pB0, gBl, 0, 1);
    STAGE(pA0, gAl, 0, 0); STAGE(pA0, gAl, 0, 1);
    STAGE(pB1, gBl, 1, 0); STAGE(pB1, gBl, 1, 1);
    asm volatile("s_waitcnt vmcnt(4)" ::: "memory");
    __builtin_amdgcn_s_barrier();

#pragma unroll 1
    for (int t = 0; t < NT; t += 2) {
        // Wrap prefetch tile index near the tail: keeps issue/waitcnt schedule
        // uniform (vmcnt(4) landing guard for tile t+1 stays valid on the last
        // iteration); wrapped data lands in buffers after their final reads.
        const int T2 = (t + 2) & (NT - 1);
        const int T3 = (t + 3) & (NT - 1);

        // ---- tile t (buf0) ----
        // ph1: Q(0,0)
        READA(pA0, 0); READB(pB0, 0);
        STAGE(pA1, gAl, t + 1, 0);
        PH_SYNC; MFMA16(0, 0); PH_END;
        // ph2: Q(0,1)
        READB(pB0, 1);
        STAGE(pA1, gAl, t + 1, 1);
        PH_SYNC; MFMA16(0, 1); PH_END;
        // ph3: Q(1,0)
        READA(pA0, 1);
        STAGE(pB0, gBl, T2, 0);
        PH_SYNC; MFMA16(1, 0); PH_END;
        // ph4: Q(1,1) + landing guard for tile t+1
        STAGE(pB0, gBl, T2, 1);
        PH_SYNC; MFMA16(1, 1); PH_END_VM;

        // ---- tile t+1 (buf1) ----
        // ph5: Q(0,0)
        READA(pA1, 0); READB(pB1, 0);
        STAGE(pA0, gAl, T2, 0);
        PH_SYNC; MFMA16(0, 0); PH_END;
        // ph6: Q(0,1)
        READB(pB1, 1);
        STAGE(pA0, gAl, T2, 1);
        PH_SYNC; MFMA16(0, 1); PH_END;
        // ph7: Q(1,0)
        READA(pA1, 1);
        STAGE(pB1, gBl, T3, 0);
        PH_SYNC; MFMA16(1, 0); PH_END;
        // ph8: Q(1,1) + landing guard for tile t+2
        STAGE(pB1, gBl, T3, 1);
        PH_SYNC; MFMA16(1, 1); PH_END_VM;
    }

    // Epilogue: d2 = max(x2 + c2 - 2*cross, 0); out = exp(f*d2)
    const int orow0 = row0 + wr * 128;
    const int ocol0 = col0 + wc * 64;
    float csv[4], fsv[4];
    int cidx[4];
#pragma unroll
    for (int n = 0; n < 4; ++n) {
        const int c = ocol0 + n * 16 + lrow;
        cidx[n] = c;
        csv[n] = csq[c];
        fsv[n] = fsc[c];
    }
#pragma unroll
    for (int m = 0; m < 8; ++m) {
        const int rb = orow0 + m * 16 + lhi * 4;
        const float4 xs = *(const float4*)(xsq + rb);
        const float xv[4] = {xs.x, xs.y, xs.z, xs.w};
#pragma unroll
        for (int n = 0; n < 4; ++n) {
#pragma unroll
            for (int j = 0; j < 4; ++j) {
                float d2 = fmaxf(xv[j] + csv[n] - 2.0f * acc[m][n][j], 0.0f);
                out[(size_t)(rb + j) * TN + cidx[n]] = __expf(fsv[n] * d2);
            }
        }
    }
}

extern "C" void kernel_launch(void* const* d_in, const int* in_sizes, int n_in,
                              void* d_out, int out_size, void* d_ws, size_t ws_size,
                              hipStream_t stream) {
    const float* inp = (const float*)d_in[0];  // [TM, TK]
    const float* ctr = (const float*)d_in[1];  // [TN, TK]
    const float* ls  = (const float*)d_in[2];  // [TN]
    float* out = (float*)d_out;

    // workspace layout (~42 MB)
    ushort* Abf = (ushort*)d_ws;
    ushort* Bbf = Abf + (size_t)TM * TK;
    float* xsq = (float*)(Bbf + (size_t)TN * TK);
    float* csq = xsq + TM;
    float* fsc = csq + TN;

    rowsq_cvt<<<TM, 256, 0, stream>>>(inp, Abf, xsq);
    rowsq_cvt<<<TN, 256, 0, stream>>>(ctr, Bbf, csq);
    scale_k<<<(TN + 255) / 256, 256, 0, stream>>>(ls, fsc);

    rbf_gemm<<<(TM / 256) * (TN / 256), 512, 0, stream>>>(Abf, Bbf, xsq, csq, fsc, out);
}